// Round 1
// baseline (370.116 us; speedup 1.0000x reference)
//
#include <hip/hip_runtime.h>

// ApsUp: polyphase 2x upsample (per-batch phase) + circular pad + depthwise
// 3x3 binomial blur, fused into a single gather kernel.
//
// Closed form: for output (oy,ox) with phase p (r=p&1, c=p>>1):
//   u=(oy-r)&127, v=(ox-c)&127
//   i_lo=u>>1, i_hi=((u+1)&127)>>1  (duplicate when u even -> weight 2)
//   out = (x[i_lo,j_lo]+x[i_lo,j_hi]+x[i_hi,j_lo]+x[i_hi,j_hi]) * (1/16)

#define BB 16
#define CC 256
#define NN 64   // input spatial; output is 2N=128

__global__ __launch_bounds__(256) void aps_up_kernel(
    const float* __restrict__ inp,     // [16,256,64,64]
    const int*   __restrict__ phase,   // [16]
    float*       __restrict__ out)     // [16,256,128,128]
{
    const int tid = blockIdx.x * 256 + threadIdx.x;   // one float4 of output

    // layout: 32 threads per 128-px output row; 4096 threads per (b,ch) plane
    const int lane_in_row = tid & 31;
    const int oy    = (tid >> 5) & 127;
    const int plane = tid >> 12;            // b*256 + ch
    const int b     = plane >> 8;

    const int p = phase[b];
    const int r = p & 1;
    const int c = p >> 1;

    // rows
    const int u  = (oy - r) & 127;
    const int i0 = u >> 1;                  // in [0,63]
    const int i1 = ((u + 1) & 127) >> 1;    // wraps 127 -> 0

    // columns: 4 outputs need 3 input cols k0..k0+2 (mod 64)
    const int ox0 = lane_in_row << 2;
    const int v0  = (ox0 - c) & 127;
    const int k0  = v0 >> 1;
    const int k1  = (k0 + 1) & 63;
    const int k2  = (k0 + 2) & 63;

    const float* base = inp + (size_t)plane * (NN * NN);
    const float* row0 = base + i0 * NN;
    const float* row1 = base + i1 * NN;

    const float s0 = row0[k0] + row1[k0];
    const float s1 = row0[k1] + row1[k1];
    const float s2 = row0[k2] + row1[k2];

    // column parity c is uniform per batch (and per block), so no divergence
    float4 o;
    if (c == 0) {
        // v0 even: taps (k0,k0),(k0,k1),(k1,k1),(k1,k2)
        o = make_float4(s0 + s0, s0 + s1, s1 + s1, s1 + s2);
    } else {
        // v0 odd: taps (k0,k1),(k1,k1),(k1,k2),(k2,k2)
        o = make_float4(s0 + s1, s1 + s1, s1 + s2, s2 + s2);
    }
    const float sc = 0.0625f;
    o.x *= sc; o.y *= sc; o.z *= sc; o.w *= sc;

    reinterpret_cast<float4*>(out)[tid] = o;
}

extern "C" void kernel_launch(void* const* d_in, const int* in_sizes, int n_in,
                              void* d_out, int out_size, void* d_ws, size_t ws_size,
                              hipStream_t stream) {
    const float* inp   = (const float*)d_in[0];
    const int*   phase = (const int*)d_in[1];
    float*       out   = (float*)d_out;

    // out_size = 16*256*128*128 = 67,108,864 floats; 4 per thread
    const int total_threads = out_size / 4;            // 16,777,216
    const int block = 256;
    const int grid  = total_threads / block;           // 65,536
    aps_up_kernel<<<grid, block, 0, stream>>>(inp, phase, out);
}

// Round 3
// 308.460 us; speedup vs baseline: 1.1999x; 1.1999x over previous
//
#include <hip/hip_runtime.h>

// ApsUp: polyphase 2x upsample (per-batch phase) + circular pad + depthwise
// 3x3 binomial blur, fused into a single gather kernel.
//
// Closed form per output (oy,ox), phase p (r=p&1, c=p>>1):
//   u=(oy-r)&127 -> rows i0=u>>1, i1=((u+1)&127)>>1 (dup when u even = weight 2)
//   v=(ox-c)&127 -> cols analogously; out = sum of 4 taps * 1/16.
//
// Thread = 8 consecutive output cols of one row:
//   2 coalesced float4 loads (row i0, row i1 at input col 4j) -> col sums s0..s3
//   boundary sum via one __shfl rotate inside the 16-lane row group (wrap free)
//   2 coalesced 16B non-temporal stores (native vector type for the builtin).

typedef float v4f __attribute__((ext_vector_type(4)));

__global__ __launch_bounds__(256) void aps_up_kernel(
    const float* __restrict__ inp,     // [16,256,64,64]
    const int*   __restrict__ phase,   // [16]
    float*       __restrict__ out)     // [16,256,128,128]
{
    const int g = blockIdx.x * 256 + threadIdx.x;  // one thread = 8 output floats

    const int j     = g & 15;          // input float4-column (16 per 64-col row)
    const int oy    = (g >> 4) & 127;  // output row
    const int plane = g >> 11;         // b*256 + ch (2048 threads per plane; 8 blocks, no straddle)
    const int b     = plane >> 8;

    const int p = phase[b];
    const int r = p & 1;
    const int c = p >> 1;              // block-uniform -> no divergence

    // blur rows (vertical [1,2,1] folded: duplicate row when u even)
    const int u  = (oy - r) & 127;
    const int i0 = u >> 1;
    const int i1 = ((u + 1) & 127) >> 1;   // wraps 127 -> row 0

    const v4f* basef4 = reinterpret_cast<const v4f*>(inp) + (size_t)plane * 1024;
    const v4f a = basef4[i0 * 16 + j];
    const v4f d = basef4[i1 * 16 + j];

    // column sums over the two blur rows
    const v4f s = a + d;
    const float s0 = s.x, s1 = s.y, s2 = s.z, s3 = s.w;

    const int lane = threadIdx.x & 63;
    const int grp  = lane & 48;        // base of this 16-lane row group

    v4f o0, o1;
    if (c == 0) {
        // need s[4j+4] = next lane's s0 (lane 15 wraps to lane 0 = col 0)
        const int src = grp | ((j + 1) & 15);
        const float s4 = __shfl(s0, src, 64);
        o0 = (v4f){s0 + s0, s0 + s1, s1 + s1, s1 + s2};
        o1 = (v4f){s2 + s2, s2 + s3, s3 + s3, s3 + s4};
    } else {
        // need s[4j-1] = prev lane's s3 (lane 0 wraps to lane 15 = col 63)
        const int src = grp | ((j - 1) & 15);
        const float sm1 = __shfl(s3, src, 64);
        o0 = (v4f){sm1 + s0, s0 + s0, s0 + s1, s1 + s1};
        o1 = (v4f){s1 + s2, s2 + s2, s2 + s3, s3 + s3};
    }
    const float sc = 0.0625f;
    o0 *= sc;
    o1 *= sc;

    v4f* outp = reinterpret_cast<v4f*>(out) + (size_t)g * 2;
    __builtin_nontemporal_store(o0, outp);
    __builtin_nontemporal_store(o1, outp + 1);
}

extern "C" void kernel_launch(void* const* d_in, const int* in_sizes, int n_in,
                              void* d_out, int out_size, void* d_ws, size_t ws_size,
                              hipStream_t stream) {
    const float* inp   = (const float*)d_in[0];
    const int*   phase = (const int*)d_in[1];
    float*       out   = (float*)d_out;

    // out_size = 16*256*128*128 = 67,108,864 floats; 8 per thread
    const int total_threads = out_size / 8;            // 8,388,608
    const int block = 256;
    const int grid  = total_threads / block;           // 32,768
    aps_up_kernel<<<grid, block, 0, stream>>>(inp, phase, out);
}